// Round 4
// baseline (227.350 us; speedup 1.0000x reference)
//
#include <hip/hip_runtime.h>
#include <hip/hip_bf16.h>
#include <hip/hip_fp16.h>

// ---------------- problem constants (from reference setup_inputs) ----------
#define N_NODES_C   51200
#define NODE_PER_G  200
#define NGRAPH      256
#define HEADS       4
#define HID         64
#define FDIM        256         // HEADS*HID
#define IN_DIM_C    200
#define E_RAND_C    819200      // 16 * N_NODES
#define RAND_PER_G  3200        // E_RAND / NGRAPH
#define EPG         3400        // RAND_PER_G + NODE_PER_G self loops
#define NEG_SLOPE   0.2f

typedef _Float16 f16x8 __attribute__((ext_vector_type(8)));
typedef float    f32x4 __attribute__((ext_vector_type(4)));

// ---------------------------------------------------------------------------
// W[K][256] f32  ->  Wt[256][K] f16   (tiny, once per launch)
// ---------------------------------------------------------------------------
__global__ __launch_bounds__(256) void transpose_to_f16(
    const float* __restrict__ W, _Float16* __restrict__ Wt, int K)
{
    int k = blockIdx.x;
    int n = threadIdx.x;
    Wt[(size_t)n * K + k] = (_Float16)W[(size_t)k * 256 + n];
}

// ---------------------------------------------------------------------------
// fp16-MFMA GEMM: C[M,256](f16) = A[M,K] @ B[K,256].  A f32 or f16 row-major
// (AF16), B pre-transposed f16 [256][K].  128x128 tile, BK=32, 4 waves (2x2),
// per-wave 64x64 via 4x4 frags of mfma_f32_16x16x32_f16.  Paired-row XOR
// swizzle -> conflict-free ds_read_b128 on frag reads AND staging writes.
// ---------------------------------------------------------------------------
__device__ __forceinline__ int swzoff(int m, int kg) {
    int pair = m >> 1;
    int slot = (((m & 1) << 2) | kg) ^ (pair & 7);
    return pair * 64 + slot * 8;          // element (f16) offset
}

__device__ __forceinline__ f16x8 cvt8(float4 a, float4 b) {
    f16x8 r;
    r[0] = (_Float16)a.x; r[1] = (_Float16)a.y;
    r[2] = (_Float16)a.z; r[3] = (_Float16)a.w;
    r[4] = (_Float16)b.x; r[5] = (_Float16)b.y;
    r[6] = (_Float16)b.z; r[7] = (_Float16)b.w;
    return r;
}

template <bool AF16>
__global__ __launch_bounds__(256) void gemm_f16(
    const void* __restrict__ A_, const _Float16* __restrict__ Bt,
    _Float16* __restrict__ C, int K)
{
    __shared__ _Float16 As[128 * 32];
    __shared__ _Float16 Bs[128 * 32];

    const int tid  = threadIdx.x;
    const int row0 = blockIdx.x * 128;
    const int col0 = blockIdx.y * 128;
    const int gm   = tid >> 2;       // staging granule outer index (m or n)
    const int gk   = tid & 3;        // k-granule within BK (8 f16 each)
    const int ntiles = (K + 31) >> 5;

    f32x4 acc[4][4];
#pragma unroll
    for (int i = 0; i < 4; ++i)
#pragma unroll
        for (int j = 0; j < 4; ++j) acc[i][j] = (f32x4){0.f, 0.f, 0.f, 0.f};

    float4 a00, a01, a10, a11;       // f32-A path
    uint4  a0v, a1v;                 // f16-A path
    uint4  b0v, b1v;
    const uint4 z4 = make_uint4(0u, 0u, 0u, 0u);

    auto fetch = [&](int k0) {
        int k = k0 + gk * 8;
        if (k + 8 <= K) {
            if constexpr (AF16) {
                const _Float16* A = (const _Float16*)A_;
                a0v = *(const uint4*)&A[(size_t)(row0 + gm) * K + k];
                a1v = *(const uint4*)&A[(size_t)(row0 + gm + 64) * K + k];
            } else {
                const float* A = (const float*)A_;
                const float* pa0 = &A[(size_t)(row0 + gm) * K + k];
                const float* pa1 = &A[(size_t)(row0 + gm + 64) * K + k];
                a00 = *(const float4*)pa0; a01 = *(const float4*)(pa0 + 4);
                a10 = *(const float4*)pa1; a11 = *(const float4*)(pa1 + 4);
            }
            b0v = *(const uint4*)&Bt[(size_t)(col0 + gm) * K + k];
            b1v = *(const uint4*)&Bt[(size_t)(col0 + gm + 64) * K + k];
        } else {
            if constexpr (AF16) { a0v = a1v = z4; }
            else { a00 = a01 = a10 = a11 = make_float4(0.f, 0.f, 0.f, 0.f); }
            b0v = b1v = z4;
        }
    };

    const int w    = tid >> 6, lane = tid & 63;
    const int wm   = (w >> 1) * 64, wn = (w & 1) * 64;
    const int aoff = swzoff(lane & 15, lane >> 4) + wm * 32;
    const int boff = swzoff(lane & 15, lane >> 4) + wn * 32;
    const int oA0 = swzoff(gm, gk), oA1 = swzoff(gm + 64, gk);

    fetch(0);
    for (int t = 0; t < ntiles; ++t) {
        __syncthreads();
        if constexpr (AF16) {
            *(uint4*)&As[oA0] = a0v;
            *(uint4*)&As[oA1] = a1v;
        } else {
            *(f16x8*)&As[oA0] = cvt8(a00, a01);
            *(f16x8*)&As[oA1] = cvt8(a10, a11);
        }
        *(uint4*)&Bs[oA0] = b0v;
        *(uint4*)&Bs[oA1] = b1v;
        __syncthreads();
        if (t + 1 < ntiles) fetch((t + 1) << 5);

        f16x8 af[4], bf[4];
#pragma unroll
        for (int mi = 0; mi < 4; ++mi) af[mi] = *(const f16x8*)&As[aoff + mi * 512];
#pragma unroll
        for (int ni = 0; ni < 4; ++ni) bf[ni] = *(const f16x8*)&Bs[boff + ni * 512];
#pragma unroll
        for (int mi = 0; mi < 4; ++mi)
#pragma unroll
            for (int ni = 0; ni < 4; ++ni)
                acc[mi][ni] = __builtin_amdgcn_mfma_f32_16x16x32_f16(
                    af[mi], bf[ni], acc[mi][ni], 0, 0, 0);
    }

    // epilogue: C/D layout col = lane&15, row = (lane>>4)*4 + reg
    const int crow = row0 + wm + ((lane >> 4) << 2);
    const int ccol = col0 + wn + (lane & 15);
#pragma unroll
    for (int mi = 0; mi < 4; ++mi)
#pragma unroll
        for (int ni = 0; ni < 4; ++ni)
#pragma unroll
            for (int r = 0; r < 4; ++r)
                C[(size_t)(crow + mi * 16 + r) * FDIM + ccol + ni * 16] =
                    (_Float16)acc[mi][ni][r];
}

// ---------------------------------------------------------------------------
// Fused per-graph GAT layer.  ft/hprev are f16 [N][256].  alpha (per edge x
// head) precomputed in the scatter phase -> phase-4 inner loop is pure
// load+fma with independent iterations (2x unrolled).
// ---------------------------------------------------------------------------
template <bool RES, bool MEAN>
__global__ __launch_bounds__(1024) void gat_fused(
    const _Float16* __restrict__ ft, const int* __restrict__ src,
    const int* __restrict__ dst, const float* __restrict__ al,
    const float* __restrict__ ar, const _Float16* __restrict__ hprev,
    const float* __restrict__ Wc, const float* __restrict__ bc,
    void* __restrict__ out_)
{
    __shared__ uint2  s_ft2[NODE_PER_G * 64];        // 102400 B, 4xf16 granules
    __shared__ float  s_el[NODE_PER_G * HEADS];      // 3200 B
    __shared__ float  s_er[NODE_PER_G * HEADS];      // 3200 B
    __shared__ float  s_den[NODE_PER_G * HEADS];     // 3200 B
    __shared__ int    s_cnt[NODE_PER_G];             // 800 B
    __shared__ int    s_scan[256];                   // 1024 B
    __shared__ int    s_off[NODE_PER_G + 1];         // 804 B
    __shared__ uchar2 s_edge[RAND_PER_G];            // 6400 B
    __shared__ unsigned char s_list[EPG];            // 3400 B
    __shared__ uint2  s_alpha2[EPG];                 // 27200 B, 4xf16 per pos
    __shared__ float  s_out[2];

    const int g = blockIdx.x;
    const int tid = threadIdx.x;
    const int node0 = g * NODE_PER_G;

    // ---- phase 0: stage ft (f16, swizzled granules) + edge list -----------
    if (tid < 2) s_out[tid] = 0.f;
    if (tid < NODE_PER_G) s_cnt[tid] = 1;            // self-loop pre-counted
    {
        const _Float16* ftg = ft + (size_t)node0 * FDIM;
        for (int gi = tid; gi < NODE_PER_G * 32; gi += 1024) {
            int row = gi >> 5, c2 = (gi & 31) << 1;  // two 8B granules
            uint4 v = *(const uint4*)&ftg[((size_t)row << 8) + (c2 << 2)];
            s_ft2[row * 64 + (c2 ^ (row & 63))] = make_uint2(v.x, v.y);
            s_ft2[row * 64 + ((c2 + 1) ^ (row & 63))] = make_uint2(v.z, v.w);
        }
        for (int e = tid; e < RAND_PER_G; e += 1024) {
            int eid = g + (e << 8);                  // edge i in graph i%256
            uchar2 t;
            t.x = (unsigned char)(src[eid] - node0);
            t.y = (unsigned char)(dst[eid] - node0);
            s_edge[e] = t;
        }
    }
    __syncthreads();

    // ---- phase 1: el/er dots (tid<800) + in-degree counts -----------------
    if (tid < NODE_PER_G * HEADS) {
        int n = tid >> 2, h = tid & 3;
        const float* alh = al + h * HID;
        const float* arh = ar + h * HID;
        float se = 0.f, sr = 0.f;
#pragma unroll
        for (int d = 0; d < HID; d += 4) {
            int c = h * 16 + (d >> 2);
            uint2 u = s_ft2[n * 64 + (c ^ (n & 63))];
            float2 f01 = __half22float2(*(__half2*)&u.x);
            float2 f23 = __half22float2(*(__half2*)&u.y);
            float4 av = *(const float4*)&alh[d];
            float4 bv = *(const float4*)&arh[d];
            se += f01.x * av.x + f01.y * av.y + f23.x * av.z + f23.y * av.w;
            sr += f01.x * bv.x + f01.y * bv.y + f23.x * bv.z + f23.y * bv.w;
        }
        s_el[tid] = se;
        s_er[tid] = sr;
    }
    for (int e = tid; e < RAND_PER_G; e += 1024)
        atomicAdd(&s_cnt[s_edge[e].y], 1);
    __syncthreads();

    // ---- phase 2: scan -> bucket offsets; self-loop alpha seeds den -------
    if (tid < 256) s_scan[tid] = (tid < NODE_PER_G) ? s_cnt[tid] : 0;
    __syncthreads();
    for (int st = 1; st < 256; st <<= 1) {
        int v = 0;
        if (tid < 256) { v = s_scan[tid]; if (tid >= st) v += s_scan[tid - st]; }
        __syncthreads();
        if (tid < 256) s_scan[tid] = v;
        __syncthreads();
    }
    if (tid < NODE_PER_G) {
        int beg = s_scan[tid] - s_cnt[tid];
        s_off[tid] = beg;
        s_list[beg] = (unsigned char)tid;            // self-loop in slot 0
        s_cnt[tid] = 1;
        __half2 p01, p23;
#pragma unroll
        for (int h = 0; h < HEADS; ++h) {
            float s = s_el[tid * 4 + h] + s_er[tid * 4 + h];
            s = (s >= 0.f) ? s : NEG_SLOPE * s;
            float a = __expf(s);                     // shift-invariant softmax
            s_den[tid * 4 + h] = a;                  // direct seed (no atomic)
            __half hv = __float2half_rn(a);
            if (h == 0) p01.x = hv; else if (h == 1) p01.y = hv;
            else if (h == 2) p23.x = hv; else p23.y = hv;
        }
        uint2 u; u.x = *(unsigned*)&p01; u.y = *(unsigned*)&p23;
        s_alpha2[beg] = u;
    }
    if (tid == 0) s_off[NODE_PER_G] = EPG;
    __syncthreads();

    // ---- phase 3: scatter edges + per-edge alpha (all 4 heads) ------------
    for (int e = tid; e < RAND_PER_G; e += 1024) {
        uchar2 t = s_edge[e];
        int pos = s_off[t.y] + atomicAdd(&s_cnt[t.y], 1);
        s_list[pos] = t.x;
        __half2 p01, p23;
#pragma unroll
        for (int h = 0; h < HEADS; ++h) {
            float s = s_el[t.x * 4 + h] + s_er[t.y * 4 + h];
            s = (s >= 0.f) ? s : NEG_SLOPE * s;
            float a = __expf(s);
            atomicAdd(&s_den[t.y * 4 + h], a);
            __half hv = __float2half_rn(a);
            if (h == 0) p01.x = hv; else if (h == 1) p01.y = hv;
            else if (h == 2) p23.x = hv; else p23.y = hv;
        }
        uint2 u; u.x = *(unsigned*)&p01; u.y = *(unsigned*)&p23;
        s_alpha2[pos] = u;
    }
    __syncthreads();

    // ---- phase 4: per-node weighted aggregation (pure load+fma, 2x unroll)
    const __half* s_alpha = (const __half*)s_alpha2;
    const int wave = tid >> 6, lane = tid & 63;
    const int h  = lane >> 4;
    const int c0 = lane << 2;
    float wout0 = 0.f, wout1 = 0.f;

    for (int n = wave; n < NODE_PER_G; n += 16) {
        const int beg = s_off[n], end = s_off[n + 1];
        float4 acc  = make_float4(0.f, 0.f, 0.f, 0.f);
        float4 acc2 = make_float4(0.f, 0.f, 0.f, 0.f);
        int j = beg;
        for (; j + 2 <= end; j += 2) {
            int sl0 = s_list[j], sl1 = s_list[j + 1];
            float a0 = __half2float(s_alpha[j * 4 + h]);
            float a1 = __half2float(s_alpha[(j + 1) * 4 + h]);
            uint2 u0 = s_ft2[sl0 * 64 + (lane ^ (sl0 & 63))];
            uint2 u1 = s_ft2[sl1 * 64 + (lane ^ (sl1 & 63))];
            float2 f00 = __half22float2(*(__half2*)&u0.x);
            float2 f01 = __half22float2(*(__half2*)&u0.y);
            float2 f10 = __half22float2(*(__half2*)&u1.x);
            float2 f11 = __half22float2(*(__half2*)&u1.y);
            acc.x  = fmaf(a0, f00.x, acc.x);  acc.y  = fmaf(a0, f00.y, acc.y);
            acc.z  = fmaf(a0, f01.x, acc.z);  acc.w  = fmaf(a0, f01.y, acc.w);
            acc2.x = fmaf(a1, f10.x, acc2.x); acc2.y = fmaf(a1, f10.y, acc2.y);
            acc2.z = fmaf(a1, f11.x, acc2.z); acc2.w = fmaf(a1, f11.y, acc2.w);
        }
        if (j < end) {
            int sl0 = s_list[j];
            float a0 = __half2float(s_alpha[j * 4 + h]);
            uint2 u0 = s_ft2[sl0 * 64 + (lane ^ (sl0 & 63))];
            float2 f00 = __half22float2(*(__half2*)&u0.x);
            float2 f01 = __half22float2(*(__half2*)&u0.y);
            acc.x = fmaf(a0, f00.x, acc.x);  acc.y = fmaf(a0, f00.y, acc.y);
            acc.z = fmaf(a0, f01.x, acc.z);  acc.w = fmaf(a0, f01.y, acc.w);
        }
        acc.x += acc2.x; acc.y += acc2.y; acc.z += acc2.z; acc.w += acc2.w;

        float rd = 1.f / s_den[n * 4 + h];
        acc.x *= rd; acc.y *= rd; acc.z *= rd; acc.w *= rd;
        if (RES) {
            uint2 r2 = *(const uint2*)&hprev[(size_t)(node0 + n) * FDIM + c0];
            float2 r01 = __half22float2(*(__half2*)&r2.x);
            float2 r23 = __half22float2(*(__half2*)&r2.y);
            acc.x += r01.x; acc.y += r01.y; acc.z += r23.x; acc.w += r23.y;
        }
        acc.x = (acc.x > 0.f) ? acc.x : expm1f(acc.x);
        acc.y = (acc.y > 0.f) ? acc.y : expm1f(acc.y);
        acc.z = (acc.z > 0.f) ? acc.z : expm1f(acc.z);
        acc.w = (acc.w > 0.f) ? acc.w : expm1f(acc.w);
        if (!MEAN) {
            _Float16* out = (_Float16*)out_;
            __half2 o01, o23;
            o01.x = __float2half_rn(acc.x); o01.y = __float2half_rn(acc.y);
            o23.x = __float2half_rn(acc.z); o23.y = __float2half_rn(acc.w);
            uint2 u; u.x = *(unsigned*)&o01; u.y = *(unsigned*)&o23;
            *(uint2*)&out[(size_t)(node0 + n) * FDIM + c0] = u;
        } else {
            acc.x += __shfl_xor(acc.x, 16); acc.x += __shfl_xor(acc.x, 32);
            acc.y += __shfl_xor(acc.y, 16); acc.y += __shfl_xor(acc.y, 32);
            acc.z += __shfl_xor(acc.z, 16); acc.z += __shfl_xor(acc.z, 32);
            acc.w += __shfl_xor(acc.w, 16); acc.w += __shfl_xor(acc.w, 32);
            if (lane < 16) {
                acc.x *= 0.25f; acc.y *= 0.25f; acc.z *= 0.25f; acc.w *= 0.25f;
                const float* wp = Wc + (((size_t)n * HID + c0) << 1);
                float4 w0 = *(const float4*)&wp[0];
                float4 w1 = *(const float4*)&wp[4];
                wout0 += acc.x * w0.x + acc.y * w0.z + acc.z * w1.x + acc.w * w1.z;
                wout1 += acc.x * w0.y + acc.y * w0.w + acc.z * w1.y + acc.w * w1.w;
            }
        }
    }

    if (MEAN) {
        float* out = (float*)out_;
#pragma unroll
        for (int m = 8; m >= 1; m >>= 1) {
            wout0 += __shfl_xor(wout0, m);
            wout1 += __shfl_xor(wout1, m);
        }
        if (lane == 0) { atomicAdd(&s_out[0], wout0); atomicAdd(&s_out[1], wout1); }
        __syncthreads();
        if (tid < 2) out[g * 2 + tid] = s_out[tid] + bc[tid];
    }
}

// ---------------------------------------------------------------------------
extern "C" void kernel_launch(void* const* d_in, const int* in_sizes, int n_in,
                              void* d_out, int out_size, void* d_ws, size_t ws_size,
                              hipStream_t stream) {
    const float* feat = (const float*)d_in[0];
    const int*   src  = (const int*)d_in[1];
    const int*   dst  = (const int*)d_in[2];
    const float* W0   = (const float*)d_in[3];
    const float* al0  = (const float*)d_in[4];
    const float* ar0  = (const float*)d_in[5];
    const float* W1   = (const float*)d_in[6];
    const float* al1  = (const float*)d_in[7];
    const float* ar1  = (const float*)d_in[8];
    const float* Wc   = (const float*)d_in[9];
    const float* bc   = (const float*)d_in[10];
    float* out = (float*)d_out;

    // workspace layout (f16): ft | h0 | W0t | W1t
    _Float16* ft  = (_Float16*)d_ws;
    _Float16* h0  = ft + (size_t)N_NODES_C * FDIM;
    _Float16* W0t = h0 + (size_t)N_NODES_C * FDIM;
    _Float16* W1t = W0t + (size_t)FDIM * IN_DIM_C;

    transpose_to_f16<<<IN_DIM_C, 256, 0, stream>>>(W0, W0t, IN_DIM_C);
    transpose_to_f16<<<FDIM, 256, 0, stream>>>(W1, W1t, FDIM);

    dim3 ggrid(N_NODES_C / 128, FDIM / 128);

    // layer 0
    gemm_f16<false><<<ggrid, 256, 0, stream>>>(feat, W0t, ft, IN_DIM_C);
    gat_fused<false, false><<<NGRAPH, 1024, 0, stream>>>(
        ft, src, dst, al0, ar0, nullptr, nullptr, nullptr, h0);

    // layer 1 (+ fused head-mean and Wc readout)
    gemm_f16<true><<<ggrid, 256, 0, stream>>>(h0, W1t, ft, FDIM);
    gat_fused<true, true><<<NGRAPH, 1024, 0, stream>>>(
        ft, src, dst, al1, ar1, h0, Wc, bc, out);
}